// Round 1
// baseline (143.574 us; speedup 1.0000x reference)
//
#include <hip/hip_runtime.h>
#include <math.h>

// Problem constants (match reference)
constexpr int T_LEN = 15360;
constexpr int B_DIM = 64;
constexpr int C_DIM = 64;
constexpr int NTHR  = 256;
constexpr int PT    = T_LEN / NTHR;       // 60 contiguous elems / thread
constexpr int VPT   = T_LEN / 4 / NTHR;   // 15 float4 / thread
constexpr int KHALF = 12;                 // k=25 taps -> halo 12

__global__ __launch_bounds__(NTHR, 2)
void emg_inject_kernel(const float* __restrict__ x,
                       const float* __restrict__ noise,
                       const float* __restrict__ apply_u,
                       const float* __restrict__ frac_u,
                       const float* __restrict__ ch_u,
                       const float* __restrict__ burst_u,
                       const float* __restrict__ start_u,
                       const float* __restrict__ snr_u,
                       float* __restrict__ out)
{
    const int row = blockIdx.x;          // row = b*C + c
    const int b   = row >> 6;
    const int c   = row & 63;
    const int tid = threadIdx.x;

    __shared__ float s_ch[C_DIM];
    __shared__ float s_red[8];
    __shared__ float s_noise[T_LEN];

    if (tid < C_DIM) s_ch[tid] = ch_u[(size_t)b * C_DIM + tid];
    __syncthreads();

    // --- channel selection: rank(ch_u[b,c]) < n_aff (argsort-of-argsort rank,
    //     stable tie-break by index) ---
    const float myv = s_ch[c];
    int rank = 0;
    #pragma unroll 8
    for (int i = 0; i < C_DIM; ++i) {
        float v = s_ch[i];
        rank += (v < myv || (v == myv && i < c)) ? 1 : 0;
    }
    const float frac = frac_u[b];
    int n_aff = (int)floorf(((float)C_DIM * frac) * 0.5f);  // (c*frac)*MAX_CH
    n_aff = max(1, n_aff);
    const bool affected = (apply_u[b] <= 0.4f) && (rank < n_aff);

    const float*  xrow = x   + (size_t)row * T_LEN;
    float*        orow = out + (size_t)row * T_LEN;
    const float4* x4   = (const float4*)xrow;
    float4*       o4   = (float4*)orow;

    if (!affected) {
        // pure copy: out = x  (coalesced float4)
        #pragma unroll
        for (int it = 0; it < VPT; ++it) {
            int idx = tid + it * NTHR;
            o4[idx] = x4[idx];
        }
        return;
    }

    // ---------------- affected row ----------------
    // Stage noise row -> LDS, x row -> registers, accumulate sum(x^2)
    const float4* n4 = (const float4*)(noise + (size_t)row * T_LEN);
    float4* s_n4 = (float4*)s_noise;
    float4 xr[VPT];
    float sumx2 = 0.f;
    #pragma unroll
    for (int it = 0; it < VPT; ++it) {
        int idx = tid + it * NTHR;
        float4 nv = n4[idx];
        s_n4[idx] = nv;
        float4 xv = x4[idx];
        xr[it] = xv;
        sumx2 += xv.x * xv.x + xv.y * xv.y + xv.z * xv.z + xv.w * xv.w;
    }

    // --- burst mask parameters (block-uniform, matches reference f32 math) ---
    const float bu   = burst_u[b];
    const float bfr  = 0.1f + bu * 0.4f;                  // BF_LO + u*(BF_HI-BF_LO)
    const int   blen = (int)floorf((float)T_LEN * bfr);
    int tmb = T_LEN - blen; if (tmb < 1) tmb = 1;
    const int   start = (int)floorf(start_u[b] * (float)tmb);
    const int   elen  = min(25, blen / 4);
    const float sf    = (float)start;
    const float endf  = sf + (float)blen;
    const float ef    = (float)elen;
    const float denom = fmaxf(ef - 1.0f, 1.0f);
    const float inv_denom = 1.0f / denom;
    const float head_end  = sf + ef;        // exact small ints in f32
    const float tail_beg  = endf - ef;

    __syncthreads();   // noise row staged

    // --- sliding 25-tap window; emg_b into registers; sum(emg_b^2) ---
    const int lo = tid * PT;
    float w = 0.f;
    for (int u = lo - KHALF; u <= lo + KHALF; ++u) {
        float v = (u >= 0 && u < T_LEN) ? s_noise[u] : 0.f;
        w += v;
    }
    float e[PT];
    float sume2 = 0.f;
    const float inv_k = 1.0f / 25.0f;
    #pragma unroll
    for (int j = 0; j < PT; ++j) {
        const int t  = lo + j;
        const float nv  = s_noise[t];
        const float emg = nv - w * inv_k;
        const float tt  = (float)t;
        const bool  inb = (tt >= sf) && (tt < endf);
        float ramped;
        if (tt < head_end)       ramped = (tt - sf) * inv_denom;
        else if (tt >= tail_beg) ramped = (endf - 1.0f - tt) * inv_denom;
        else                     ramped = 1.0f;
        const float m  = inb ? ((ef > 1.0f) ? ramped : 1.0f) : 0.0f;
        const float eb = emg * m;
        e[j] = eb;
        sume2 += eb * eb;
        // slide window to t+1
        const int ai = t + KHALF + 1;
        const int si = t - KHALF;
        const float av = (ai < T_LEN) ? s_noise[ai] : 0.f;
        const float sv = (si >= 0)    ? s_noise[si] : 0.f;
        w += av - sv;
    }

    __syncthreads();   // all halo reads done -> safe to overwrite

    // write emg_b back over s_noise (lo = 240B*tid -> 16B aligned)
    #pragma unroll
    for (int j = 0; j < PT; j += 4) {
        float4 v = make_float4(e[j], e[j + 1], e[j + 2], e[j + 3]);
        *(float4*)&s_noise[lo + j] = v;
    }

    // --- block reduction of sumx2 / sume2 ---
    float v1 = sumx2, v2 = sume2;
    #pragma unroll
    for (int off = 32; off > 0; off >>= 1) {
        v1 += __shfl_down(v1, off, 64);
        v2 += __shfl_down(v2, off, 64);
    }
    const int wave = tid >> 6;
    if ((tid & 63) == 0) { s_red[wave] = v1; s_red[wave + 4] = v2; }
    __syncthreads();   // covers s_red writes AND emg_b writeback
    const float sx = s_red[0] + s_red[1] + s_red[2] + s_red[3];
    const float se = s_red[4] + s_red[5] + s_red[6] + s_red[7];

    const float sig_p = sqrtf(sx / (float)T_LEN) + 1e-8f;
    const float noi_p = sqrtf(se / (float)T_LEN) + 1e-8f;
    const float snr   = 0.5f + snr_u[b] * 2.5f;
    const float coef  = sig_p / (noi_p * snr);

    // --- output: out = x + coef * emg_b (coalesced) ---
    #pragma unroll
    for (int it = 0; it < VPT; ++it) {
        int idx = tid + it * NTHR;
        float4 ev = s_n4[idx];
        float4 xv = xr[it];
        float4 ov;
        ov.x = xv.x + coef * ev.x;
        ov.y = xv.y + coef * ev.y;
        ov.z = xv.z + coef * ev.z;
        ov.w = xv.w + coef * ev.w;
        o4[idx] = ov;
    }
}

extern "C" void kernel_launch(void* const* d_in, const int* in_sizes, int n_in,
                              void* d_out, int out_size, void* d_ws, size_t ws_size,
                              hipStream_t stream) {
    const float* x       = (const float*)d_in[0];
    const float* noise   = (const float*)d_in[1];
    const float* apply_u = (const float*)d_in[2];
    const float* frac_u  = (const float*)d_in[3];
    const float* ch_u    = (const float*)d_in[4];
    const float* burst_u = (const float*)d_in[5];
    const float* start_u = (const float*)d_in[6];
    const float* snr_u   = (const float*)d_in[7];
    float* out = (float*)d_out;

    dim3 grid(B_DIM * C_DIM);
    dim3 block(NTHR);
    emg_inject_kernel<<<grid, block, 0, stream>>>(
        x, noise, apply_u, frac_u, ch_u, burst_u, start_u, snr_u, out);
}